// Round 10
// baseline (402.077 us; speedup 1.0000x reference)
//
#include <hip/hip_runtime.h>
#include <stdint.h>

typedef __attribute__((ext_vector_type(8))) short bf16x8;   // 8 bf16 = 4 VGPRs
typedef __attribute__((ext_vector_type(4))) float f32x4;

#define NBLK 256            // edge-chunk blocks for the deterministic counting sort
#define BSH  7              // bucket = 128 nodes
#define BSZ  128

typedef __attribute__((address_space(1))) const unsigned int gu32;
typedef __attribute__((address_space(3))) unsigned int lu32;

__device__ __forceinline__ float bf2f(unsigned short b) {
    union { unsigned u; float f; } c; c.u = ((unsigned)b) << 16; return c.f;
}
__device__ __forceinline__ float bflo(unsigned w) {
    union { unsigned u; float f; } c; c.u = w << 16; return c.f;
}
__device__ __forceinline__ float bfhi(unsigned w) {
    union { unsigned u; float f; } c; c.u = w & 0xffff0000u; return c.f;
}
__device__ __forceinline__ unsigned short f2bf(float f) {
    union { float f; unsigned u; } c; c.f = f;
    unsigned u = c.u;
    u += 0x7fffu + ((u >> 16) & 1u);          // round-to-nearest-even
    return (unsigned short)(u >> 16);
}

__global__ void GNNEncoder_317827579954_kernel() {}

// Fused prep: blocks [0,512) transpose/convert W1,W2 -> bf16 Wt; blocks [512,512+NBLK)
// compute the per-chunk bucket histogram (cmat column). Flags are computed
// block-locally (cheap) and persisted once for downstream kernels.
__global__ __launch_bounds__(256) void k_prep(const void* __restrict__ Wa,
                                              unsigned short* __restrict__ Wta,
                                              const void* __restrict__ Wb,
                                              unsigned short* __restrict__ Wtb,
                                              const unsigned* __restrict__ x,
                                              const int* __restrict__ ei, int E,
                                              int* __restrict__ cmat, int nb,
                                              int* __restrict__ flags) {
    __shared__ int lc[512];
    __shared__ int sflag;
    int t = threadIdx.x;
    int bb = blockIdx.x;
    if (bb < 512) {
        // ---- cvtT part: needs f32-vs-bf16 flag of dense inputs ----
        if (t < 64) {
            int pl = 0;
            for (int i = t; i < 256; i += 64) {
                unsigned u = x[i] & 0xffffu;
                unsigned e2 = (u >> 7) & 0xffu;
                if ((e2 >= 100u && e2 <= 145u) || u == 0u) ++pl;
            }
            for (int off = 32; off; off >>= 1) pl += __shfl_down(pl, off);
            if (t == 0) sflag = (pl >= 192) ? 0 : 1;     // 1 = f32
        }
        __syncthreads();
        int af32 = sflag;
        if (bb == 0 && t == 0) flags[0] = af32;
        const void* W = bb < 256 ? Wa : Wb;
        unsigned short* Wt = bb < 256 ? Wta : Wtb;
        int n = bb & 255;
        unsigned short v;
        if (af32) v = f2bf(((const float*)W)[t * 256 + n]);
        else      v = ((const unsigned short*)W)[t * 256 + n];
        Wt[n * 256 + t] = v;
    } else {
        // ---- cmat part: needs int64-vs-int32 flag of edge_index ----
        int b = bb - 512;
        if (t < 64) {
            int n = E < 64 ? E : 64;
            unsigned long long nz = __ballot(t < n ? (ei[2 * t + 1] != 0) : 0);
            if (t == 0) sflag = (nz == 0ull) ? 1 : 0;    // 1 = int64
        }
        for (int i = t; i < nb; i += 256) lc[i] = 0;
        __syncthreads();
        int i64 = sflag;
        if (b == 0 && t == 0) flags[1] = i64;
        int chunk = (E + NBLK - 1) / NBLK;
        int beg = b * chunk;
        int end = beg + chunk; if (end > E) end = E;
        for (int i = beg + t; i < end; i += 256) {
            int d = i64 ? ei[2 * E + 2 * i] : ei[E + i];
            atomicAdd(&lc[d >> BSH], 1);
        }
        __syncthreads();
        for (int j = t; j < nb; j += 256) cmat[j * NBLK + b] = lc[j];
    }
}

// Per-bucket-row exclusive scan of cmat (in place) + row total.
__global__ __launch_bounds__(256) void k_rowscan(int* __restrict__ cmat,
                                                 int* __restrict__ btot) {
    __shared__ int sc[256];
    int j = blockIdx.x;
    int t = threadIdx.x;
    int* row = cmat + j * NBLK;
    int v = row[t];
    sc[t] = v;
    __syncthreads();
    for (int off = 1; off < 256; off <<= 1) {
        int u = (t >= off) ? sc[t - off] : 0;
        __syncthreads();
        sc[t] += u;
        __syncthreads();
    }
    row[t] = sc[t] - v;                  // exclusive prefix within row
    if (t == 255) btot[j] = sc[255];     // bucket total
}

// In-LDS exclusive scan of btot (nb <= 511) -> pr[0..nb] (pr[nb] = E).
// 256 threads handle 512 slots via pair-sum + Hillis.
__device__ __forceinline__ void scan_btot(const int* __restrict__ btot, int nb,
                                          int* bo, int* pr, int* ps, int t) {
    for (int j = t; j < 512; j += 256) bo[j] = (j < nb) ? btot[j] : 0;
    __syncthreads();
    ps[t] = bo[2 * t] + bo[2 * t + 1];
    __syncthreads();
    for (int off = 1; off < 256; off <<= 1) {
        int u = (t >= off) ? ps[t - off] : 0;
        __syncthreads();
        ps[t] += u;
        __syncthreads();
    }
    int pp = (t == 0) ? 0 : ps[t - 1];
    pr[2 * t] = pp;
    pr[2 * t + 1] = pp + bo[2 * t];
    __syncthreads();
}

__global__ __launch_bounds__(256) void k_fillmat(const int* __restrict__ ei, int E,
                                                 const int* __restrict__ flags,
                                                 const int* __restrict__ cmat,
                                                 const int* __restrict__ btot,
                                                 unsigned* __restrict__ tmp, int nb) {
    __shared__ int cur[512];
    __shared__ int bo[512], pr[512], ps[256];
    int t = threadIdx.x, b = blockIdx.x;
    scan_btot(btot, nb, bo, pr, ps, t);
    for (int j = t; j < nb; j += 256) cur[j] = cmat[j * NBLK + b] + pr[j];
    __syncthreads();
    int chunk = (E + NBLK - 1) / NBLK;
    int beg = b * chunk;
    int end = beg + chunk; if (end > E) end = E;
    int i64 = flags[1];
    for (int i = beg + t; i < end; i += 256) {
        int s, d;
        if (i64) { s = ei[2 * i]; d = ei[2 * E + 2 * i]; }
        else     { s = ei[i];     d = ei[E + i]; }
        int p = atomicAdd(&cur[d >> BSH], 1);        // LDS atomic only
        tmp[p] = ((unsigned)s << BSH) | (unsigned)(d & (BSZ - 1));
    }
}

// Per-bucket: 128-key LDS degree count + scan -> offs, dinv, then node-sorted
// CSR fill. Bucket offsets recomputed in-LDS from btot (no boff array).
__global__ __launch_bounds__(256) void k_bbuild(const unsigned* __restrict__ tmp,
                                                const int* __restrict__ btot,
                                                int* __restrict__ offs,
                                                float* __restrict__ dinv,
                                                int* __restrict__ csr, int N, int nb) {
    __shared__ int kc[BSZ], cur[BSZ];
    __shared__ int bo[512], pr[512], ps[256];
    int b = blockIdx.x;
    int t = threadIdx.x;
    int base = b << BSH;
    scan_btot(btot, nb, bo, pr, ps, t);
    int beg = pr[b];
    int end = pr[b + 1];                  // b+1 <= nb <= 511
    if (t < BSZ) kc[t] = 0;
    __syncthreads();
    for (int i = beg + t; i < end; i += 256) {
        unsigned u = tmp[i];
        atomicAdd(&kc[u & (BSZ - 1u)], 1);
    }
    __syncthreads();
    int d = (t < BSZ) ? kc[t] : 0;
    if (t < BSZ) ps[t] = d;               // reuse ps for the 128-scan (t<128 region)
    __syncthreads();
    for (int off = 1; off < BSZ; off <<= 1) {
        int u2 = 0;
        if (t < BSZ && t >= off) u2 = ps[t - off];
        __syncthreads();
        if (t < BSZ) ps[t] += u2;
        __syncthreads();
    }
    if (t < BSZ) {
        int ex = ps[t] - d;
        cur[t] = ex;
        int v = base + t;
        if (v < N) {
            offs[v] = beg + ex;
            dinv[v] = rsqrtf((float)(d + 1));   // +1 = self loop
        }
    }
    if (t == 0 && b == nb - 1) offs[N] = end;
    __syncthreads();
    for (int i = beg + t; i < end; i += 256) {
        unsigned u = tmp[i];
        int p = atomicAdd(&cur[u & (BSZ - 1u)], 1);
        csr[beg + p] = (int)(u >> BSH);
    }
}

// C[M,256] = dinv[row] * (A[M,256] @ Bt^T), A in f32 (converted in-flight) or bf16.
// B K-slices double-buffered in LDS via global_load_lds (16 B, XOR-swizzled chunks);
// C staged through the same LDS for fully-coalesced uint4 stores.
__global__ __launch_bounds__(256) void k_gemm(const void* __restrict__ Araw,
                                              const unsigned short* __restrict__ Bt,
                                              unsigned short* __restrict__ C,
                                              const float* __restrict__ dinv,
                                              const int* __restrict__ flags, int useflag,
                                              int M) {
    __shared__ unsigned short smem[16384];   // 32 KB: B dbuf 2x16KB, then C 64x256 tile
    int tid  = threadIdx.x;
    int lane = tid & 63;
    int wave = tid >> 6;
    int q = lane >> 4;
    int r = lane & 15;
    int rowBase0 = blockIdx.x * 64;
    int rowBase = rowBase0 + wave * 16;
    int af32 = useflag ? flags[0] : 0;       // wave-uniform branch

    int arow = rowBase + r;
    arow = arow < M ? arow : M - 1;
    const unsigned short* aptrh = (const unsigned short*)Araw + (size_t)arow * 256;
    const float*          aptrf = (const float*)Araw + (size_t)arow * 256;

    auto stage = [&](int buf, int kk) {
#pragma unroll
        for (int j = 0; j < 4; ++j) {
            int c = wave * 256 + j * 64 + lane;
            int col = c >> 2;
            int kc = (c & 3) ^ (col & 3);
            const unsigned short* src = Bt + col * 256 + kk + kc * 8;
            unsigned short* dst = smem + buf * 8192 + (wave * 4 + j) * 512;
            __builtin_amdgcn_global_load_lds((gu32*)src, (lu32*)dst, 16, 0, 0);
        }
    };

    stage(0, 0);
    __syncthreads();                         // vmcnt(0) drain: buf0 ready

    f32x4 acc[16] = {};
    int cur = 0;
    for (int kk = 0; kk < 256; kk += 32) {
        if (kk < 224) stage(cur ^ 1, kk + 32);   // prefetch next slice first (T3)
        bf16x8 a;
        if (af32) {
            float4 v0 = *(const float4*)(aptrf + kk + q * 8);
            float4 v1 = *(const float4*)(aptrf + kk + q * 8 + 4);
            union { unsigned short s[8]; bf16x8 v; } ua;
            ua.s[0] = f2bf(v0.x); ua.s[1] = f2bf(v0.y); ua.s[2] = f2bf(v0.z); ua.s[3] = f2bf(v0.w);
            ua.s[4] = f2bf(v1.x); ua.s[5] = f2bf(v1.y); ua.s[6] = f2bf(v1.z); ua.s[7] = f2bf(v1.w);
            a = ua.v;
        } else {
            a = *(const bf16x8*)(aptrh + kk + q * 8);
        }
#pragma unroll
        for (int nt = 0; nt < 16; ++nt) {
            int col = nt * 16 + r;
            const unsigned short* bp = smem + cur * 8192 + col * 32 + (q ^ (col & 3)) * 8;
            bf16x8 b = *(const bf16x8*)bp;
            acc[nt] = __builtin_amdgcn_mfma_f32_16x16x32_bf16(a, b, acc[nt], 0, 0, 0);
        }
        __syncthreads();                     // drains next-slice loads; guards buf reuse
        cur ^= 1;
    }

    // epilogue: reuse smem as 64x256 bf16 C tile
    float ds4[4];
#pragma unroll
    for (int r2 = 0; r2 < 4; ++r2) {
        int row = rowBase + q * 4 + r2;
        ds4[r2] = (row < M) ? dinv[row] : 0.f;
    }
    int lrow0 = wave * 16 + q * 4;
#pragma unroll
    for (int nt = 0; nt < 16; ++nt) {
        int col = nt * 16 + r;
#pragma unroll
        for (int r2 = 0; r2 < 4; ++r2)
            smem[(lrow0 + r2) * 256 + col] = f2bf(acc[nt][r2] * ds4[r2]);
    }
    __syncthreads();
#pragma unroll
    for (int p = 0; p < 8; ++p) {
        int idx = wave * 4096 + p * 512 + lane * 8;   // in shorts
        int grow = rowBase0 + (idx >> 8);
        if (grow < M)
            *(uint4*)(C + (size_t)grow * 256 + (idx & 255)) = *(const uint4*)(smem + idx);
    }
}

// Pure row-sum aggregation over dinv-prescaled rows XWs. One wave per node;
// lane owns 8 channels (uint4); lane-half (0/1) takes even/odd edges, x4 unroll
// = 8 edges in flight.  out[v] = dinv[v] * (sum_e XWs[src_e] + XWs[v]) + b
__global__ __launch_bounds__(256) void k_agg(const unsigned short* __restrict__ XWs,
                                             const int* __restrict__ csr,
                                             const int* __restrict__ offs,
                                             const float* __restrict__ dinv,
                                             const void* __restrict__ bias,
                                             void* __restrict__ out,
                                             int relu, int final_, const int* __restrict__ flags,
                                             int N) {
    int v = blockIdx.x * 4 + (threadIdx.x >> 6);
    if (v >= N) return;
    int lane = threadIdx.x & 63;
    int half = lane >> 5;            // 0 or 1
    int cl   = (lane & 31) * 8;      // 8 channels, 16 B
    float acc[8] = {};
    int beg = offs[v], end = offs[v + 1];
    int e = beg;
    for (; e + 8 <= end; e += 8) {
        int s[4]; uint4 u[4];
#pragma unroll
        for (int j = 0; j < 4; ++j) s[j] = csr[e + 2 * j + half];
#pragma unroll
        for (int j = 0; j < 4; ++j) u[j] = *(const uint4*)(XWs + (size_t)s[j] * 256 + cl);
#pragma unroll
        for (int j = 0; j < 4; ++j) {
            acc[0] += bflo(u[j].x); acc[1] += bfhi(u[j].x);
            acc[2] += bflo(u[j].y); acc[3] += bfhi(u[j].y);
            acc[4] += bflo(u[j].z); acc[5] += bfhi(u[j].z);
            acc[6] += bflo(u[j].w); acc[7] += bfhi(u[j].w);
        }
    }
    for (; e + 2 <= end; e += 2) {
        int s = csr[e + half];
        uint4 u = *(const uint4*)(XWs + (size_t)s * 256 + cl);
        acc[0] += bflo(u.x); acc[1] += bfhi(u.x);
        acc[2] += bflo(u.y); acc[3] += bfhi(u.y);
        acc[4] += bflo(u.z); acc[5] += bfhi(u.z);
        acc[6] += bflo(u.w); acc[7] += bfhi(u.w);
    }
    if (e < end && half == 0) {
        int s = csr[e];
        uint4 u = *(const uint4*)(XWs + (size_t)s * 256 + cl);
        acc[0] += bflo(u.x); acc[1] += bfhi(u.x);
        acc[2] += bflo(u.y); acc[3] += bfhi(u.y);
        acc[4] += bflo(u.z); acc[5] += bfhi(u.z);
        acc[6] += bflo(u.w); acc[7] += bfhi(u.w);
    }
#pragma unroll
    for (int k = 0; k < 8; ++k) acc[k] += __shfl_xor(acc[k], 32);
    if (half) return;                // lanes 0..31 finish the row

    float dv = dinv[v];
    uint4 su = *(const uint4*)(XWs + (size_t)v * 256 + cl);   // self (prescaled)
    float sf[8];
    sf[0] = bflo(su.x); sf[1] = bfhi(su.x);
    sf[2] = bflo(su.y); sf[3] = bfhi(su.y);
    sf[4] = bflo(su.z); sf[5] = bfhi(su.z);
    sf[6] = bflo(su.w); sf[7] = bfhi(su.w);
    float bb[8];
    if (flags[0]) {
        const float4* bp = (const float4*)((const float*)bias + cl);
        float4 b0 = bp[0], b1 = bp[1];
        bb[0] = b0.x; bb[1] = b0.y; bb[2] = b0.z; bb[3] = b0.w;
        bb[4] = b1.x; bb[5] = b1.y; bb[6] = b1.z; bb[7] = b1.w;
    } else {
        uint4 bu = *(const uint4*)((const unsigned short*)bias + cl);
        bb[0] = bflo(bu.x); bb[1] = bfhi(bu.x);
        bb[2] = bflo(bu.y); bb[3] = bfhi(bu.y);
        bb[4] = bflo(bu.z); bb[5] = bfhi(bu.z);
        bb[6] = bflo(bu.w); bb[7] = bfhi(bu.w);
    }
    float r[8];
#pragma unroll
    for (int k = 0; k < 8; ++k) {
        float t = dv * (acc[k] + sf[k]) + bb[k];
        r[k] = relu ? fmaxf(t, 0.f) : t;
    }
    if (final_ && flags[0]) {
        float* op = (float*)out + (size_t)v * 256 + cl;
        float4 o0, o1;
        o0.x = r[0]; o0.y = r[1]; o0.z = r[2]; o0.w = r[3];
        o1.x = r[4]; o1.y = r[5]; o1.z = r[6]; o1.w = r[7];
        ((float4*)op)[0] = o0; ((float4*)op)[1] = o1;
    } else {
        uint4 o;
        o.x = (unsigned)f2bf(r[0]) | ((unsigned)f2bf(r[1]) << 16);
        o.y = (unsigned)f2bf(r[2]) | ((unsigned)f2bf(r[3]) << 16);
        o.z = (unsigned)f2bf(r[4]) | ((unsigned)f2bf(r[5]) << 16);
        o.w = (unsigned)f2bf(r[6]) | ((unsigned)f2bf(r[7]) << 16);
        *(uint4*)((unsigned short*)out + (size_t)v * 256 + cl) = o;
    }
}

extern "C" void kernel_launch(void* const* d_in, const int* in_sizes, int n_in,
                              void* d_out, int out_size, void* d_ws, size_t ws_size,
                              hipStream_t stream) {
    (void)n_in; (void)out_size; (void)ws_size;
    const void* x  = d_in[0];
    const int*  ei = (const int*)d_in[1];
    const void* W1 = d_in[2];
    const void* b1 = d_in[3];
    const void* W2 = d_in[4];
    const void* b2 = d_in[5];

    int N = in_sizes[0] / 256;          // 50000
    int E = in_sizes[1] / 2;            // 1600000
    int NB = (N + BSZ - 1) / BSZ;       // 391 buckets of 128 nodes

    char* p = (char*)d_ws;
    auto alloc = [&](size_t bytes) {
        char* r = p;
        p += (bytes + 255) & ~(size_t)255;
        return r;
    };
    int*            flags  = (int*)alloc(8);
    int*            btot   = (int*)alloc(512 * 4);
    int*            offs   = (int*)alloc(((size_t)N + 1) * 4);
    float*          dinv   = (float*)alloc((size_t)N * 4);
    unsigned short* wt1    = (unsigned short*)alloc(256 * 256 * 2);
    unsigned short* wt2    = (unsigned short*)alloc(256 * 256 * 2);
    int*            csr    = (int*)alloc((size_t)E * 4);
    unsigned short* buf0   = (unsigned short*)alloc((size_t)N * 256 * 2);
    unsigned short* buf1   = (unsigned short*)alloc((size_t)N * 256 * 2);
    unsigned*       tmp    = (unsigned*)buf1;   // dead until gemm2 writes buf1
    int*            cmat   = (int*)buf0;        // dead until k_agg1 writes buf0
    unsigned short* xw1    = (unsigned short*)d_out;  // layer-1 XW scratch in d_out

    k_prep<<<512 + NBLK, 256, 0, stream>>>(W1, wt1, W2, wt2,
                                           (const unsigned*)x, ei, E, cmat, NB, flags);
    k_rowscan<<<NB, 256, 0, stream>>>(cmat, btot);
    k_fillmat<<<NBLK, 256, 0, stream>>>(ei, E, flags, cmat, btot, tmp, NB);
    k_bbuild<<<NB, 256, 0, stream>>>(tmp, btot, offs, dinv, csr, N, NB);

    int gAgg = (N + 3) / 4;
    k_gemm<<<(N + 63) / 64, 256, 0, stream>>>(x, wt1, xw1, dinv, flags, 1, N);   // dinv*(X@W1)
    k_agg<<<gAgg, 256, 0, stream>>>(xw1, csr, offs, dinv, b1,
                                    (void*)buf0, 1, 0, flags, N);                // h -> buf0
    k_gemm<<<(N + 63) / 64, 256, 0, stream>>>(buf0, wt2, buf1, dinv, flags, 0, N); // dinv*(H@W2)
    k_agg<<<gAgg, 256, 0, stream>>>(buf1, csr, offs, dinv, b2,
                                    d_out, 0, 1, flags, N);                      // final
}